// Round 10
// baseline (1083.561 us; speedup 1.0000x reference)
//
#include <hip/hip_runtime.h>

#define NN 100000
#define EC 6400000
#define ED 400000
#define BN_EPS 1e-5f
#define NSB ((NN + 255) >> 8)    // 391 buckets of 256 nodes
#define NCH 256                  // edge chunks == scatter/hist grid
#define CSR_CAP 21504            // LDS CSR build capacity (pad-16 worst case ~19K)
#define PSLACK 4096              // per-bucket csr padding slack (256 nodes x <=15)
#define CHUNK_OF(E) (((((E) + NCH - 1) / NCH) + 3) & ~3)   // 4-aligned chunk

// ---------------- preprocessing (R5-proven; per-node segments pad-to-P) -------

__global__ __launch_bounds__(1024)
void hist_pass(const int* __restrict__ ei, int E, int* __restrict__ bhist) {
    __shared__ int h[NSB];
    for (int i = threadIdx.x; i < NSB; i += 1024) h[i] = 0;
    __syncthreads();
    int k = blockIdx.x;
    int chunk = CHUNK_OF(E);
    int beg = k * chunk, end = min(E, beg + chunk);
    for (int e = beg + threadIdx.x * 4; e < end; e += 1024 * 4) {
        int4 d4 = *(const int4*)&ei[E + e];
        atomicAdd(&h[d4.x >> 8], 1);
        atomicAdd(&h[d4.y >> 8], 1);
        atomicAdd(&h[d4.z >> 8], 1);
        atomicAdd(&h[d4.w >> 8], 1);
    }
    __syncthreads();
    for (int i = threadIdx.x; i < NSB; i += 1024) bhist[i * NCH + k] = h[i];
}

__global__ __launch_bounds__(256)
void row_scan(int* __restrict__ bhist, int* __restrict__ total) {
    int b = blockIdx.x;
    int* row = bhist + b * NCH;
    __shared__ int wsum[4];
    int lane = threadIdx.x & 63, w = threadIdx.x >> 6;
    int v = row[threadIdx.x];
    int x = v;
    #pragma unroll
    for (int sh = 1; sh < 64; sh <<= 1) { int y = __shfl_up(x, sh); if (lane >= sh) x += y; }
    if (lane == 63) wsum[w] = x;
    __syncthreads();
    int wb = 0;
    #pragma unroll
    for (int j = 0; j < 4; ++j) if (j < w) wb += wsum[j];
    row[threadIdx.x] = wb + x - v;
    if (threadIdx.x == 255) total[b] = wb + x;
}

// bbase: packed-array bases (real counts). cbase: csr bases (padded upper
// bound: ceil + PSLACK slack for per-node pad-to-P), 4-aligned.
__global__ void bucket_base(const int* __restrict__ total,
                            int* __restrict__ bbase, int* __restrict__ cbase) {
    __shared__ int wsum[4], wsum2[4];
    __shared__ int carry, carry2;
    if (threadIdx.x == 0) { carry = 0; carry2 = 0; }
    __syncthreads();
    int lane = threadIdx.x & 63, w = threadIdx.x >> 6;
    for (int s = 0; s < NSB; s += 256) {
        int idx = s + threadIdx.x;
        int v  = (idx < NSB) ? total[idx] : 0;
        int v2 = (idx < NSB) ? (((total[idx] + 3) & ~3) + PSLACK) : 0;
        int x = v, x2 = v2;
        #pragma unroll
        for (int sh = 1; sh < 64; sh <<= 1) {
            int y = __shfl_up(x, sh);  if (lane >= sh) x += y;
            int y2 = __shfl_up(x2, sh); if (lane >= sh) x2 += y2;
        }
        if (lane == 63) { wsum[w] = x; wsum2[w] = x2; }
        __syncthreads();
        int wb = 0, wb2 = 0;
        #pragma unroll
        for (int j = 0; j < 4; ++j) if (j < w) { wb += wsum[j]; wb2 += wsum2[j]; }
        int all = wsum[0] + wsum[1] + wsum[2] + wsum[3];
        int all2 = wsum2[0] + wsum2[1] + wsum2[2] + wsum2[3];
        if (idx < NSB) { bbase[idx] = carry + wb + x - v; cbase[idx] = carry2 + wb2 + x2 - v2; }
        __syncthreads();
        if (threadIdx.x == 0) { carry += all; carry2 += all2; }
        __syncthreads();
    }
}

__global__ __launch_bounds__(1024)
void scatter_pairs(const int* __restrict__ ei, int E,
                   const int* __restrict__ bhist, const int* __restrict__ bbase,
                   unsigned* __restrict__ packed) {
    __shared__ int cur[NSB];
    int k = blockIdx.x;
    for (int b = threadIdx.x; b < NSB; b += 1024)
        cur[b] = bbase[b] + bhist[b * NCH + k];
    __syncthreads();
    int chunk = CHUNK_OF(E);
    int beg = k * chunk, end = min(E, beg + chunk);
    for (int e = beg + threadIdx.x * 4; e < end; e += 1024 * 4) {
        int4 s4 = *(const int4*)&ei[e];
        int4 d4 = *(const int4*)&ei[E + e];
        { int p = atomicAdd(&cur[d4.x >> 8], 1); packed[p] = (unsigned)s4.x | ((unsigned)(d4.x & 255) << 17); }
        { int p = atomicAdd(&cur[d4.y >> 8], 1); packed[p] = (unsigned)s4.y | ((unsigned)(d4.y & 255) << 17); }
        { int p = atomicAdd(&cur[d4.z >> 8], 1); packed[p] = (unsigned)s4.z | ((unsigned)(d4.z & 255) << 17); }
        { int p = atomicAdd(&cur[d4.w >> 8], 1); packed[p] = (unsigned)s4.w | ((unsigned)(d4.w & 255) << 17); }
    }
}

// per-node segments padded to P; pad slots filled with a duplicate real
// neighbor (or self for deg=0) so padded gather addresses are benign.
template<int P>
__global__ __launch_bounds__(256)
void sb_csr(const unsigned* __restrict__ packed,
            const int* __restrict__ bbase, const int* __restrict__ total,
            const int* __restrict__ cbase,
            int* __restrict__ csr, int* __restrict__ offs, int* __restrict__ deg,
            float* __restrict__ inv) {
    __shared__ int h[256];
    __shared__ int loff[256];
    __shared__ int ws2[4];
    __shared__ int ptot_s;
    __shared__ int ebuf[CSR_CAP];
    int b = blockIdx.x;
    int ebeg = bbase[b], ecnt = total[b], cbeg = cbase[b];
    int node0 = b << 8;
    int nn = min(256, NN - node0);
    h[threadIdx.x] = 0;
    __syncthreads();
    for (int e = threadIdx.x; e < ecnt; e += 256)
        atomicAdd(&h[packed[ebeg + e] >> 17], 1);
    __syncthreads();
    {
        int lane = threadIdx.x & 63, w = threadIdx.x >> 6;
        int v = h[threadIdx.x];
        int pv = (v + P - 1) & ~(P - 1);          // padded slot size
        int x = pv;
        #pragma unroll
        for (int sh = 1; sh < 64; sh <<= 1) { int y = __shfl_up(x, sh); if (lane >= sh) x += y; }
        if (lane == 63) ws2[w] = x;
        __syncthreads();
        int wb = 0;
        #pragma unroll
        for (int j = 0; j < 4; ++j) if (j < w) wb += ws2[j];
        int excl = wb + x - pv;
        loff[threadIdx.x] = excl;
        if (threadIdx.x == 255) ptot_s = wb + x;
        if (threadIdx.x < nn) {
            int node = node0 + threadIdx.x;
            offs[node] = cbeg + excl;
            deg[node]  = v;
            inv[node]  = 1.0f / (float)(v > 1 ? v : 1);
        }
    }
    __syncthreads();
    int ptot = ptot_s;
    if (ptot <= CSR_CAP) {
        for (int e = threadIdx.x; e < ecnt; e += 256) {
            unsigned u = packed[ebeg + e];
            int p = atomicAdd(&loff[u >> 17], 1);
            ebuf[p] = (int)(u & 0x1FFFF);
        }
        __syncthreads();
        if (threadIdx.x < 256) {                  // fill padding per node
            int t = threadIdx.x;
            int dg = h[t];
            int base = loff[t] - dg;              // cursor ended at base+dg
            int pdeg = (dg + P - 1) & ~(P - 1);
            int fillv = dg ? ebuf[base] : min(node0 + t, NN - 1);
            for (int p = dg; p < pdeg; ++p) ebuf[base + p] = fillv;
        }
        __syncthreads();
        for (int e = threadIdx.x; e < ptot; e += 256) csr[cbeg + e] = ebuf[e];
    } else {   // overflow fallback (never fires for this data)
        for (int e = threadIdx.x; e < ecnt; e += 256) {
            unsigned u = packed[ebeg + e];
            int p = atomicAdd(&loff[u >> 17], 1);
            csr[cbeg + p] = (int)(u & 0x1FFFF);
        }
        __syncthreads();
        if (threadIdx.x < 256) {
            int t = threadIdx.x;
            int dg = h[t];
            int base = loff[t] - dg;
            int pdeg = (dg + P - 1) & ~(P - 1);
            int fillv = dg ? csr[cbeg + base] : min(node0 + t, NN - 1);
            for (int p = dg; p < pdeg; ++p) csr[cbeg + base + p] = fillv;
        }
    }
}

// prep: x (f32 [NN,5]) -> f32 padded [NN,8]; W1 (8x5) -> padded 8x8
__global__ __launch_bounds__(256)
void prep_misc(const float* __restrict__ x, const float* __restrict__ W1l,
               const float* __restrict__ W1r, float* __restrict__ xp,
               float* __restrict__ W1lp, float* __restrict__ W1rp) {
    int t = blockIdx.x * 256 + threadIdx.x;
    if (t < 64) {
        int f = t >> 3, k = t & 7;
        W1lp[t] = (k < 5) ? W1l[f * 5 + k] : 0.f;
        W1rp[t] = (k < 5) ? W1r[f * 5 + k] : 0.f;
    }
    for (int idx = t; idx < NN * 8; idx += gridDim.x * 256) {
        int f = idx & 7, i = idx >> 3;
        xp[idx] = (f < 5) ? x[i * 5 + f] : 0.f;
    }
}

// ---------------- fused SAGE layer v5: pair-lane gather ----------------
// R8/R9 both stall at ~10 cyc/edge despite 4x different in-flight loads ->
// throughput wall on per-line L1 misses. Each edge's 32B row was TWO dwordx4
// instructions = 2 lookups of the SAME 64B line. Now 2 lanes per edge load
// the two 16B halves in ONE instruction -> TA merges -> 1 lookup/edge.
// 16 lanes/node (8 edge slots x 2 halves), 4 nodes/wave, SLOTS edges/iter.
template<int SLOTS, bool APPLY_BN>
__global__ __launch_bounds__(256)
void sage_pair(const float* __restrict__ hin,
               const float* __restrict__ stats_in,   // padded: [k*16]=sum, [(8+k)*16]=sumsq
               const float* __restrict__ gin, const float* __restrict__ bin,
               const int* __restrict__ offs, const int* __restrict__ deg,
               const int* __restrict__ csr, const float* __restrict__ inv,
               const float* __restrict__ Wl, const float* __restrict__ Wr,
               float* __restrict__ hout, float* __restrict__ stats_out) {
    __shared__ float bl[16];
    int tid = threadIdx.x;
    if (tid < 16) bl[tid] = 0.f;
    __syncthreads();
    int wave = tid >> 6, lane = tid & 63;
    int l = lane & 15, gn = lane >> 4;            // node-group lane, node in wave
    int hf = l & 1, es = l >> 1;                  // half (0:f0-3,1:f4-7), edge slot
    int f = l & 7;

    float sc[8], sh[8];
    #pragma unroll
    for (int k = 0; k < 8; ++k) { sc[k] = 1.f; sh[k] = 0.f; }
    if constexpr (APPLY_BN) {
        #pragma unroll
        for (int k = 0; k < 8; ++k) {
            float m = stats_in[k * 16] * (1.f / NN);
            float v = stats_in[(8 + k) * 16] * (1.f / NN) - m * m;
            float is = rsqrtf(v + BN_EPS);
            sc[k] = gin[k] * is;
            sh[k] = bin[k] - m * sc[k];
        }
    }
    float wl[8], wr[8];
    #pragma unroll
    for (int k = 0; k < 8; ++k) { wl[k] = Wl[f * 8 + k]; wr[k] = Wr[f * 8 + k]; }

    int i = (blockIdx.x * 4 + wave) * 4 + gn;     // exact cover: NN = 6250*16
    int d = deg[i];
    int o = offs[i];
    const int off4 = hf * 4;
    float a0 = 0, a1 = 0, a2 = 0, a3 = 0;
    for (int b = 0; b < d; b += SLOTS) {
        int e1 = b + es;
        int c1 = csr[o + e1];                     // 2 lanes share each dword: merged
        unsigned s1 = min((unsigned)c1 & 0x1FFFFu, (unsigned)(NN - 1));
        float4 r1 = *(const float4*)(hin + (size_t)s1 * 8 + off4);
        float m1 = (e1 < d) ? 1.f : 0.f;
        if constexpr (SLOTS == 16) {
            int c2 = csr[o + e1 + 8];
            unsigned s2 = min((unsigned)c2 & 0x1FFFFu, (unsigned)(NN - 1));
            float4 r2 = *(const float4*)(hin + (size_t)s2 * 8 + off4);
            float m2 = (e1 + 8 < d) ? 1.f : 0.f;
            a0 = fmaf(r1.x, m1, a0); a1 = fmaf(r1.y, m1, a1);
            a2 = fmaf(r1.z, m1, a2); a3 = fmaf(r1.w, m1, a3);
            a0 = fmaf(r2.x, m2, a0); a1 = fmaf(r2.y, m2, a1);
            a2 = fmaf(r2.z, m2, a2); a3 = fmaf(r2.w, m2, a3);
        } else {
            a0 = fmaf(r1.x, m1, a0); a1 = fmaf(r1.y, m1, a1);
            a2 = fmaf(r1.z, m1, a2); a3 = fmaf(r1.w, m1, a3);
        }
    }
    // reduce over 8 edge slots (lane bits 1..3), preserving half parity
    #pragma unroll
    for (int msk = 2; msk <= 8; msk <<= 1) {
        a0 += __shfl_xor(a0, msk); a1 += __shfl_xor(a1, msk);
        a2 += __shfl_xor(a2, msk); a3 += __shfl_xor(a3, msk);
    }
    // exchange halves: every lane gets all 8 feature sums
    float b0 = __shfl_xor(a0, 1), b1 = __shfl_xor(a1, 1);
    float b2 = __shfl_xor(a2, 1), b3 = __shfl_xor(a3, 1);
    float ac[8];
    ac[0] = hf ? b0 : a0; ac[1] = hf ? b1 : a1; ac[2] = hf ? b2 : a2; ac[3] = hf ? b3 : a3;
    ac[4] = hf ? a0 : b0; ac[5] = hf ? a1 : b1; ac[6] = hf ? a2 : b2; ac[7] = hf ? a3 : b3;
    // self row: each lane loads its half, exchange likewise
    float4 hh = *(const float4*)(hin + (size_t)i * 8 + off4);
    float c0 = __shfl_xor(hh.x, 1), c1 = __shfl_xor(hh.y, 1);
    float c2 = __shfl_xor(hh.z, 1), c3 = __shfl_xor(hh.w, 1);
    float hk[8];
    hk[0] = hf ? c0 : hh.x; hk[1] = hf ? c1 : hh.y; hk[2] = hf ? c2 : hh.z; hk[3] = hf ? c3 : hh.w;
    hk[4] = hf ? hh.x : c0; hk[5] = hf ? hh.y : c1; hk[6] = hf ? hh.z : c2; hk[7] = hf ? hh.w : c3;

    float im = inv[i];
    float dnz = (d > 0) ? 1.f : 0.f;              // BN shift only if node has neighbors
    float y = 0.f;
    #pragma unroll
    for (int k = 0; k < 8; ++k) {
        float mk = fmaf(sc[k], ac[k] * im, sh[k] * dnz);
        float hv = fmaf(sc[k], hk[k], sh[k]);
        y = fmaf(mk, wl[k], y);
        y = fmaf(hv, wr[k], y);
    }
    float n2 = y * y;
    n2 += __shfl_xor(n2, 1);
    n2 += __shfl_xor(n2, 2);
    n2 += __shfl_xor(n2, 4);
    float z = y / fmaxf(sqrtf(n2), 1e-12f);
    float r = fmaxf(z, 0.f);
    if (l < 8) {                                  // one writer per feature
        hout[(size_t)i * 8 + f] = r;              // 32B/node, nodes consecutive
        atomicAdd(&bl[f], r);
        atomicAdd(&bl[8 + f], r * r);
    }
    __syncthreads();
    if (tid < 16) atomicAdd(&stats_out[tid * 16], bl[tid]);   // 1 cache line per feature
}

__global__ void apply_bn_out(const float* __restrict__ hin,
                             const float* __restrict__ stats,
                             const float* __restrict__ g, const float* __restrict__ b,
                             float* __restrict__ out) {
    int t = blockIdx.x * blockDim.x + threadIdx.x;
    if (t >= NN * 8) return;
    int f = t & 7;
    float m = stats[f * 16] * (1.0f / NN);
    float v = stats[(8 + f) * 16] * (1.0f / NN) - m * m;
    float sc = g[f] * rsqrtf(v + BN_EPS);
    float sh = b[f] - m * sc;
    out[t] = fmaf(hin[t], sc, sh);
}

// ---------------- launch ----------------

static inline char* bump(char*& p, size_t bytes) {
    char* r = p;
    p += (bytes + 255) & ~(size_t)255;
    return r;
}

extern "C" void kernel_launch(void* const* d_in, const int* in_sizes, int n_in,
                              void* d_out, int out_size, void* d_ws, size_t ws_size,
                              hipStream_t stream) {
    const float* x   = (const float*)d_in[0];
    const int* eic   = (const int*)d_in[1];
    const int* eid   = (const int*)d_in[2];
    const float* W1l = (const float*)d_in[3];
    const float* W1r = (const float*)d_in[4];
    const float* W2l = (const float*)d_in[5];
    const float* W2r = (const float*)d_in[6];
    const float* W3l = (const float*)d_in[7];
    const float* W3r = (const float*)d_in[8];
    const float* W4l = (const float*)d_in[9];
    const float* W4r = (const float*)d_in[10];
    const float* g1 = (const float*)d_in[11];
    const float* b1 = (const float*)d_in[12];
    const float* g2 = (const float*)d_in[13];
    const float* b2 = (const float*)d_in[14];
    const float* g3 = (const float*)d_in[15];
    const float* b3 = (const float*)d_in[16];
    const float* g4 = (const float*)d_in[17];
    const float* b4 = (const float*)d_in[18];
    float* out = (float*)d_out;

    const size_t CPAD = (size_t)NSB * PSLACK + PSLACK;   // bucket padding slack

    char* p = (char*)d_ws;
    float* stats   = (float*)bump(p, 5 * 256 * 4);   // zero region (only this)
    size_t zero_bytes = (size_t)(p - (char*)d_ws);
    int*   bhist_c = (int*)  bump(p, (size_t)NSB * NCH * 4);
    int*   bhist_d = (int*)  bump(p, (size_t)NSB * NCH * 4);
    int*   total_c = (int*)  bump(p, NSB * 4);
    int*   bbase_c = (int*)  bump(p, NSB * 4);
    int*   cbase_c = (int*)  bump(p, NSB * 4);
    int*   total_d = (int*)  bump(p, NSB * 4);
    int*   bbase_d = (int*)  bump(p, NSB * 4);
    int*   cbase_d = (int*)  bump(p, NSB * 4);
    int*   offs_c  = (int*)  bump(p, NN * 4);
    int*   deg_c   = (int*)  bump(p, NN * 4);
    float* inv_c   = (float*)bump(p, NN * 4);
    int*   offs_d  = (int*)  bump(p, NN * 4);
    int*   deg_d   = (int*)  bump(p, NN * 4);
    float* inv_d   = (float*)bump(p, NN * 4);
    int*   csr_c   = (int*)  bump(p, ((size_t)EC + CPAD) * 4);
    int*   csr_d   = (int*)  bump(p, ((size_t)ED + CPAD) * 4);
    float* xp32    = (float*)bump(p, (size_t)NN * 8 * 4);
    float* W1lp    = (float*)bump(p, 64 * 4);
    float* W1rp    = (float*)bump(p, 64 * 4);
    unsigned* packed_d = (unsigned*)bump(p, (size_t)ED * 4);
    // packed_c dead after sb_csr; overlay f32 activation ping-pong buffers
    char* pc = p;
    unsigned* packed_c = (unsigned*)bump(p, (size_t)EC * 4);
    char* pr = pc;
    float* r_a = (float*)bump(pr, (size_t)NN * 8 * 4);
    float* r_b = (float*)bump(pr, (size_t)NN * 8 * 4);
    (void)ws_size; (void)in_sizes; (void)n_in; (void)out_size;

    hipMemsetAsync(d_ws, 0, zero_bytes, stream);

    hist_pass<<<NCH, 1024, 0, stream>>>(eic, EC, bhist_c);
    hist_pass<<<NCH, 1024, 0, stream>>>(eid, ED, bhist_d);
    row_scan<<<NSB, 256, 0, stream>>>(bhist_c, total_c);
    row_scan<<<NSB, 256, 0, stream>>>(bhist_d, total_d);
    bucket_base<<<1, 256, 0, stream>>>(total_c, bbase_c, cbase_c);
    bucket_base<<<1, 256, 0, stream>>>(total_d, bbase_d, cbase_d);
    scatter_pairs<<<NCH, 1024, 0, stream>>>(eic, EC, bhist_c, bbase_c, packed_c);
    scatter_pairs<<<NCH, 1024, 0, stream>>>(eid, ED, bhist_d, bbase_d, packed_d);
    sb_csr<16><<<NSB, 256, 0, stream>>>(packed_c, bbase_c, total_c, cbase_c, csr_c, offs_c, deg_c, inv_c);
    sb_csr<8><<<NSB, 256, 0, stream>>>(packed_d, bbase_d, total_d, cbase_d, csr_d, offs_d, deg_d, inv_d);
    prep_misc<<<512, 256, 0, stream>>>(x, W1l, W1r, xp32, W1lp, W1rp);

    const int LB = NN / 16;   // 6250 blocks x 4 waves x 4 nodes = exactly NN
    sage_pair<16, false><<<LB, 256, 0, stream>>>(
        xp32, nullptr, nullptr, nullptr,
        offs_c, deg_c, csr_c, inv_c, W1lp, W1rp, r_a, stats + 0);
    sage_pair<16, true><<<LB, 256, 0, stream>>>(
        r_a, stats + 0, g1, b1,
        offs_c, deg_c, csr_c, inv_c, W4l, W4r, r_b, stats + 256);
    sage_pair<8, true><<<LB, 256, 0, stream>>>(
        r_b, stats + 256, g2, b2,
        offs_d, deg_d, csr_d, inv_d, W2l, W2r, r_a, stats + 512);
    sage_pair<16, true><<<LB, 256, 0, stream>>>(
        r_a, stats + 512, g3, b3,
        offs_c, deg_c, csr_c, inv_c, W3l, W3r, r_b, stats + 768);
    sage_pair<16, true><<<LB, 256, 0, stream>>>(
        r_b, stats + 768, g4, b4,
        offs_c, deg_c, csr_c, inv_c, W3l, W3r, r_a, stats + 1024);
    apply_bn_out<<<(NN * 8 + 255) / 256, 256, 0, stream>>>(r_a, stats + 1024, g4, b4, out);
}

// Round 11
// 625.300 us; speedup vs baseline: 1.7329x; 1.7329x over previous
//
#include <hip/hip_runtime.h>
#include <hip/hip_fp16.h>

#define NN 100000
#define EC 6400000
#define ED 400000
#define BN_EPS 1e-5f
#define NSB ((NN + 255) >> 8)    // 391 buckets of 256 nodes
#define NCH 256                  // edge chunks == scatter/hist grid
#define CSR_CAP 19200            // LDS CSR build capacity (mean 16384 + slack)
#define CHUNK_OF(E) (((((E) + NCH - 1) / NCH) + 3) & ~3)   // 4-aligned chunk

// ---------------- preprocessing (Round-8 version, proven best) ----------------

__global__ __launch_bounds__(1024)
void hist_pass(const int* __restrict__ ei, int E, int* __restrict__ bhist) {
    __shared__ int h[NSB];
    for (int i = threadIdx.x; i < NSB; i += 1024) h[i] = 0;
    __syncthreads();
    int k = blockIdx.x;
    int chunk = CHUNK_OF(E);
    int beg = k * chunk, end = min(E, beg + chunk);
    for (int e = beg + threadIdx.x * 4; e < end; e += 1024 * 4) {
        int4 d4 = *(const int4*)&ei[E + e];
        atomicAdd(&h[d4.x >> 8], 1);
        atomicAdd(&h[d4.y >> 8], 1);
        atomicAdd(&h[d4.z >> 8], 1);
        atomicAdd(&h[d4.w >> 8], 1);
    }
    __syncthreads();
    for (int i = threadIdx.x; i < NSB; i += 1024) bhist[i * NCH + k] = h[i];
}

__global__ __launch_bounds__(256)
void row_scan(int* __restrict__ bhist, int* __restrict__ total) {
    int b = blockIdx.x;
    int* row = bhist + b * NCH;
    __shared__ int wsum[4];
    int lane = threadIdx.x & 63, w = threadIdx.x >> 6;
    int v = row[threadIdx.x];
    int x = v;
    #pragma unroll
    for (int sh = 1; sh < 64; sh <<= 1) { int y = __shfl_up(x, sh); if (lane >= sh) x += y; }
    if (lane == 63) wsum[w] = x;
    __syncthreads();
    int wb = 0;
    #pragma unroll
    for (int j = 0; j < 4; ++j) if (j < w) wb += wsum[j];
    row[threadIdx.x] = wb + x - v;
    if (threadIdx.x == 255) total[b] = wb + x;
}

__global__ void bucket_base(const int* __restrict__ total, int* __restrict__ bbase) {
    __shared__ int wsum[4];
    __shared__ int carry;
    if (threadIdx.x == 0) carry = 0;
    __syncthreads();
    int lane = threadIdx.x & 63, w = threadIdx.x >> 6;
    for (int s = 0; s < NSB; s += 256) {
        int idx = s + threadIdx.x;
        int v = (idx < NSB) ? total[idx] : 0;
        int x = v;
        #pragma unroll
        for (int sh = 1; sh < 64; sh <<= 1) { int y = __shfl_up(x, sh); if (lane >= sh) x += y; }
        if (lane == 63) wsum[w] = x;
        __syncthreads();
        int wb = 0;
        #pragma unroll
        for (int j = 0; j < 4; ++j) if (j < w) wb += wsum[j];
        int all = wsum[0] + wsum[1] + wsum[2] + wsum[3];
        if (idx < NSB) bbase[idx] = carry + wb + x - v;
        __syncthreads();
        if (threadIdx.x == 0) carry += all;
        __syncthreads();
    }
}

__global__ __launch_bounds__(1024)
void scatter_pairs(const int* __restrict__ ei, int E,
                   const int* __restrict__ bhist, const int* __restrict__ bbase,
                   unsigned* __restrict__ packed) {
    __shared__ int cur[NSB];
    int k = blockIdx.x;
    for (int b = threadIdx.x; b < NSB; b += 1024)
        cur[b] = bbase[b] + bhist[b * NCH + k];
    __syncthreads();
    int chunk = CHUNK_OF(E);
    int beg = k * chunk, end = min(E, beg + chunk);
    for (int e = beg + threadIdx.x * 4; e < end; e += 1024 * 4) {
        int4 s4 = *(const int4*)&ei[e];
        int4 d4 = *(const int4*)&ei[E + e];
        { int p = atomicAdd(&cur[d4.x >> 8], 1); packed[p] = (unsigned)s4.x | ((unsigned)(d4.x & 255) << 17); }
        { int p = atomicAdd(&cur[d4.y >> 8], 1); packed[p] = (unsigned)s4.y | ((unsigned)(d4.y & 255) << 17); }
        { int p = atomicAdd(&cur[d4.z >> 8], 1); packed[p] = (unsigned)s4.z | ((unsigned)(d4.z & 255) << 17); }
        { int p = atomicAdd(&cur[d4.w >> 8], 1); packed[p] = (unsigned)s4.w | ((unsigned)(d4.w & 255) << 17); }
    }
}

__global__ __launch_bounds__(256)
void sb_csr(const unsigned* __restrict__ packed,
            const int* __restrict__ bbase, const int* __restrict__ total,
            int* __restrict__ csr, int* __restrict__ offs, int* __restrict__ deg,
            float* __restrict__ inv) {
    __shared__ int h[256];
    __shared__ int loff[256];
    __shared__ int ws2[4];
    __shared__ int ebuf[CSR_CAP];
    int b = blockIdx.x;
    int ebeg = bbase[b], ecnt = total[b];
    int node0 = b << 8;
    int nn = min(256, NN - node0);
    h[threadIdx.x] = 0;
    __syncthreads();
    for (int e = threadIdx.x; e < ecnt; e += 256)
        atomicAdd(&h[packed[ebeg + e] >> 17], 1);
    __syncthreads();
    {
        int lane = threadIdx.x & 63, w = threadIdx.x >> 6;
        int v = h[threadIdx.x], x = v;
        #pragma unroll
        for (int sh = 1; sh < 64; sh <<= 1) { int y = __shfl_up(x, sh); if (lane >= sh) x += y; }
        if (lane == 63) ws2[w] = x;
        __syncthreads();
        int wb = 0;
        #pragma unroll
        for (int j = 0; j < 4; ++j) if (j < w) wb += ws2[j];
        int excl = wb + x - v;
        loff[threadIdx.x] = excl;
        if (threadIdx.x < nn) {
            int node = node0 + threadIdx.x;
            offs[node] = ebeg + excl;
            deg[node]  = v;
            inv[node]  = 1.0f / (float)(v > 1 ? v : 1);
        }
    }
    __syncthreads();
    if (ecnt <= CSR_CAP) {
        for (int e = threadIdx.x; e < ecnt; e += 256) {
            unsigned u = packed[ebeg + e];
            int p = atomicAdd(&loff[u >> 17], 1);
            ebuf[p] = (int)(u & 0x1FFFF);
        }
        __syncthreads();
        for (int e = threadIdx.x; e < ecnt; e += 256) csr[ebeg + e] = ebuf[e];
    } else {
        for (int e = threadIdx.x; e < ecnt; e += 256) {
            unsigned u = packed[ebeg + e];
            int p = atomicAdd(&loff[u >> 17], 1);
            csr[ebeg + p] = (int)(u & 0x1FFFF);
        }
    }
}

// prep: x (f32 [NN,5]) -> f32 padded [NN,8] + fp16 copy; W1 -> padded 8x8
__global__ __launch_bounds__(256)
void prep_misc(const float* __restrict__ x, const float* __restrict__ W1l,
               const float* __restrict__ W1r, float* __restrict__ xp,
               __half* __restrict__ xp16,
               float* __restrict__ W1lp, float* __restrict__ W1rp) {
    int t = blockIdx.x * 256 + threadIdx.x;
    if (t < 64) {
        int f = t >> 3, k = t & 7;
        W1lp[t] = (k < 5) ? W1l[f * 5 + k] : 0.f;
        W1rp[t] = (k < 5) ? W1r[f * 5 + k] : 0.f;
    }
    for (int idx = t; idx < NN * 8; idx += gridDim.x * 256) {
        int f = idx & 7, i = idx >> 3;
        float v = (f < 5) ? x[i * 5 + f] : 0.f;
        xp[idx] = v;
        xp16[idx] = __float2half(v);
    }
}

// ---------------- fused SAGE layer v6: fp16 gather, f32 everything else -------
// R8/R9/R10 data: cost tracks row-load INSTRUCTIONS per edge (2 for 32B f32
// rows), not MLP depth, not lane-requests. fp16 rows = 16B = ONE dwordx4 per
// edge. Accuracy: only the mean path sees fp16 (5e-4, 8x finer than R7's
// failed bf16); self-term lin_r(h_i) reads the exact f32 row; predicted
// absmax ~0.02-0.03 vs 0.114 threshold. Structure otherwise = Round-8 v3.
template<bool APPLY_BN>
__global__ __launch_bounds__(256)
void sage_layer8(const float* __restrict__ hin,       // f32 rows (self-term)
                 const __half* __restrict__ hin16,    // fp16 rows (gather)
                 const float* __restrict__ stats_in,  // [k*16]=sum, [(8+k)*16]=sumsq
                 const float* __restrict__ gin, const float* __restrict__ bin,
                 const int* __restrict__ offs, const int* __restrict__ deg,
                 const int* __restrict__ csr, const float* __restrict__ inv,
                 const float* __restrict__ Wl, const float* __restrict__ Wr,
                 float* __restrict__ hout, __half* __restrict__ hout16,
                 float* __restrict__ stats_out) {
    __shared__ float bl[16];
    int tid = threadIdx.x;
    if (tid < 16) bl[tid] = 0.f;
    __syncthreads();
    int wave = tid >> 6, lane = tid & 63, g = lane >> 3, f = lane & 7;

    float sc[8], sh[8];
    #pragma unroll
    for (int k = 0; k < 8; ++k) { sc[k] = 1.f; sh[k] = 0.f; }
    if constexpr (APPLY_BN) {
        #pragma unroll
        for (int k = 0; k < 8; ++k) {
            float m = stats_in[k * 16] * (1.f / NN);
            float v = stats_in[(8 + k) * 16] * (1.f / NN) - m * m;
            float is = rsqrtf(v + BN_EPS);
            sc[k] = gin[k] * is;
            sh[k] = bin[k] - m * sc[k];
        }
    }
    float wl[8], wr[8];
    #pragma unroll
    for (int k = 0; k < 8; ++k) { wl[k] = Wl[f * 8 + k]; wr[k] = Wr[f * 8 + k]; }

    float acc_r = 0.f, acc_r2 = 0.f;
    const int stride = gridDim.x * 32;            // blocks * 4 waves * 8 nodes
    for (int i0 = (blockIdx.x * 4 + wave) * 8; i0 < NN; i0 += stride) {
        int i = i0 + g;
        int ic = min(i, NN - 1);
        bool ok = (i < NN);
        int d = ok ? deg[ic] : 0;
        int o = offs[ic];
        float a0 = 0, a1 = 0, a2 = 0, a3 = 0, a4 = 0, a5 = 0, a6 = 0, a7 = 0;
        for (int b = 0; b < d; b += 8) {          // divergent per group: exec-masked
            int e = b + f;
            int cv = csr[o + e];                  // <=7 over-read: csr tail-padded
            float m = (e < d) ? 1.f : 0.f;
            unsigned s = min((unsigned)cv & 0x1FFFFu, (unsigned)(NN - 1));
            uint4 rv = *(const uint4*)(hin16 + (size_t)s * 8);   // ONE 16B instr/edge
            float2 p0 = __half22float2(*(const __half2*)&rv.x);
            float2 p1 = __half22float2(*(const __half2*)&rv.y);
            float2 p2 = __half22float2(*(const __half2*)&rv.z);
            float2 p3 = __half22float2(*(const __half2*)&rv.w);
            a0 = fmaf(p0.x, m, a0); a1 = fmaf(p0.y, m, a1);
            a2 = fmaf(p1.x, m, a2); a3 = fmaf(p1.y, m, a3);
            a4 = fmaf(p2.x, m, a4); a5 = fmaf(p2.y, m, a5);
            a6 = fmaf(p3.x, m, a6); a7 = fmaf(p3.y, m, a7);
        }
        #pragma unroll
        for (int msk = 1; msk < 8; msk <<= 1) {   // group-wide sums, all lanes
            a0 += __shfl_xor(a0, msk); a1 += __shfl_xor(a1, msk);
            a2 += __shfl_xor(a2, msk); a3 += __shfl_xor(a3, msk);
            a4 += __shfl_xor(a4, msk); a5 += __shfl_xor(a5, msk);
            a6 += __shfl_xor(a6, msk); a7 += __shfl_xor(a7, msk);
        }
        float im = inv[ic];
        float dnz = (d > 0) ? 1.f : 0.f;          // BN shift only if node has neighbors
        const float4* hp = (const float4*)(hin + (size_t)ic * 8);   // exact f32 self row
        float4 h0 = hp[0];
        float4 h1 = hp[1];
        float hk[8] = { h0.x, h0.y, h0.z, h0.w, h1.x, h1.y, h1.z, h1.w };
        float ac[8] = { a0, a1, a2, a3, a4, a5, a6, a7 };
        float y = 0.f;
        #pragma unroll
        for (int k = 0; k < 8; ++k) {
            float mk = fmaf(sc[k], ac[k] * im, sh[k] * dnz);
            float hh = fmaf(sc[k], hk[k], sh[k]);
            y = fmaf(mk, wl[k], y);
            y = fmaf(hh, wr[k], y);
        }
        float n2 = y * y;
        n2 += __shfl_xor(n2, 1);
        n2 += __shfl_xor(n2, 2);
        n2 += __shfl_xor(n2, 4);
        float z = y / fmaxf(sqrtf(n2), 1e-12f);
        float r = fmaxf(z, 0.f);
        r = ok ? r : 0.f;
        if (ok) {
            hout[(size_t)i * 8 + f] = r;              // f32 row (exact)
            hout16[(size_t)i * 8 + f] = __float2half(r);   // fp16 row (gather copy)
        }
        acc_r += r;
        acc_r2 += r * r;
    }
    atomicAdd(&bl[f], acc_r);
    atomicAdd(&bl[8 + f], acc_r2);
    __syncthreads();
    if (tid < 16) atomicAdd(&stats_out[tid * 16], bl[tid]);   // 1 cache line per feature
}

__global__ void apply_bn_out(const float* __restrict__ hin,
                             const float* __restrict__ stats,
                             const float* __restrict__ g, const float* __restrict__ b,
                             float* __restrict__ out) {
    int t = blockIdx.x * blockDim.x + threadIdx.x;
    if (t >= NN * 8) return;
    int f = t & 7;
    float m = stats[f * 16] * (1.0f / NN);
    float v = stats[(8 + f) * 16] * (1.0f / NN) - m * m;
    float sc = g[f] * rsqrtf(v + BN_EPS);
    float sh = b[f] - m * sc;
    out[t] = fmaf(hin[t], sc, sh);
}

// ---------------- launch ----------------

static inline char* bump(char*& p, size_t bytes) {
    char* r = p;
    p += (bytes + 255) & ~(size_t)255;
    return r;
}

extern "C" void kernel_launch(void* const* d_in, const int* in_sizes, int n_in,
                              void* d_out, int out_size, void* d_ws, size_t ws_size,
                              hipStream_t stream) {
    const float* x   = (const float*)d_in[0];
    const int* eic   = (const int*)d_in[1];
    const int* eid   = (const int*)d_in[2];
    const float* W1l = (const float*)d_in[3];
    const float* W1r = (const float*)d_in[4];
    const float* W2l = (const float*)d_in[5];
    const float* W2r = (const float*)d_in[6];
    const float* W3l = (const float*)d_in[7];
    const float* W3r = (const float*)d_in[8];
    const float* W4l = (const float*)d_in[9];
    const float* W4r = (const float*)d_in[10];
    const float* g1 = (const float*)d_in[11];
    const float* b1 = (const float*)d_in[12];
    const float* g2 = (const float*)d_in[13];
    const float* b2 = (const float*)d_in[14];
    const float* g3 = (const float*)d_in[15];
    const float* b3 = (const float*)d_in[16];
    const float* g4 = (const float*)d_in[17];
    const float* b4 = (const float*)d_in[18];
    float* out = (float*)d_out;

    char* p = (char*)d_ws;
    float* stats   = (float*)bump(p, 5 * 256 * 4);   // zero region (only this)
    size_t zero_bytes = (size_t)(p - (char*)d_ws);
    int*   bhist_c = (int*)  bump(p, (size_t)NSB * NCH * 4);
    int*   bhist_d = (int*)  bump(p, (size_t)NSB * NCH * 4);
    int*   total_c = (int*)  bump(p, NSB * 4);
    int*   bbase_c = (int*)  bump(p, NSB * 4);
    int*   total_d = (int*)  bump(p, NSB * 4);
    int*   bbase_d = (int*)  bump(p, NSB * 4);
    int*   offs_c  = (int*)  bump(p, NN * 4);
    int*   deg_c   = (int*)  bump(p, NN * 4);
    float* inv_c   = (float*)bump(p, NN * 4);
    int*   offs_d  = (int*)  bump(p, NN * 4);
    int*   deg_d   = (int*)  bump(p, NN * 4);
    float* inv_d   = (float*)bump(p, NN * 4);
    int*   csr_c   = (int*)  bump(p, ((size_t)EC + 64) * 4);   // +64 over-read pad
    int*   csr_d   = (int*)  bump(p, ((size_t)ED + 64) * 4);
    float* xp32    = (float*)bump(p, (size_t)NN * 8 * 4);
    __half* xp16   = (__half*)bump(p, (size_t)NN * 8 * 2);
    float* W1lp    = (float*)bump(p, 64 * 4);
    float* W1rp    = (float*)bump(p, 64 * 4);
    unsigned* packed_d = (unsigned*)bump(p, (size_t)ED * 4);
    // packed_c dead after sb_csr; overlay activation ping-pong (f32 + fp16)
    char* pc = p;
    unsigned* packed_c = (unsigned*)bump(p, (size_t)EC * 4);
    char* pr = pc;
    float*  r_a   = (float*) bump(pr, (size_t)NN * 8 * 4);
    float*  r_b   = (float*) bump(pr, (size_t)NN * 8 * 4);
    __half* h16_a = (__half*)bump(pr, (size_t)NN * 8 * 2);
    __half* h16_b = (__half*)bump(pr, (size_t)NN * 8 * 2);
    (void)ws_size; (void)in_sizes; (void)n_in; (void)out_size; (void)packed_c;

    hipMemsetAsync(d_ws, 0, zero_bytes, stream);

    hist_pass<<<NCH, 1024, 0, stream>>>(eic, EC, bhist_c);
    hist_pass<<<NCH, 1024, 0, stream>>>(eid, ED, bhist_d);
    row_scan<<<NSB, 256, 0, stream>>>(bhist_c, total_c);
    row_scan<<<NSB, 256, 0, stream>>>(bhist_d, total_d);
    bucket_base<<<1, 256, 0, stream>>>(total_c, bbase_c);
    bucket_base<<<1, 256, 0, stream>>>(total_d, bbase_d);
    scatter_pairs<<<NCH, 1024, 0, stream>>>(eic, EC, bhist_c, bbase_c, packed_c);
    scatter_pairs<<<NCH, 1024, 0, stream>>>(eid, ED, bhist_d, bbase_d, packed_d);
    sb_csr<<<NSB, 256, 0, stream>>>(packed_c, bbase_c, total_c, csr_c, offs_c, deg_c, inv_c);
    sb_csr<<<NSB, 256, 0, stream>>>(packed_d, bbase_d, total_d, csr_d, offs_d, deg_d, inv_d);
    prep_misc<<<512, 256, 0, stream>>>(x, W1l, W1r, xp32, xp16, W1lp, W1rp);

    const int LB = 2048;   // 8192 waves x 8 nodes/wave per grid-iteration
    sage_layer8<false><<<LB, 256, 0, stream>>>(
        xp32, xp16, nullptr, nullptr, nullptr,
        offs_c, deg_c, csr_c, inv_c, W1lp, W1rp, r_a, h16_a, stats + 0);
    sage_layer8<true><<<LB, 256, 0, stream>>>(
        r_a, h16_a, stats + 0, g1, b1,
        offs_c, deg_c, csr_c, inv_c, W4l, W4r, r_b, h16_b, stats + 256);
    sage_layer8<true><<<LB, 256, 0, stream>>>(
        r_b, h16_b, stats + 256, g2, b2,
        offs_d, deg_d, csr_d, inv_d, W2l, W2r, r_a, h16_a, stats + 512);
    sage_layer8<true><<<LB, 256, 0, stream>>>(
        r_a, h16_a, stats + 512, g3, b3,
        offs_c, deg_c, csr_c, inv_c, W3l, W3r, r_b, h16_b, stats + 768);
    sage_layer8<true><<<LB, 256, 0, stream>>>(
        r_b, h16_b, stats + 768, g4, b4,
        offs_c, deg_c, csr_c, inv_c, W3l, W3r, r_a, h16_a, stats + 1024);
    apply_bn_out<<<(NN * 8 + 255) / 256, 256, 0, stream>>>(r_a, stats + 1024, g4, b4, out);
}